// Round 11
// baseline (83.118 us; speedup 1.0000x reference)
//
#include <hip/hip_runtime.h>

// 9x9 clipped box-SUM on (8,3,1024,1024) f32 — float2/lane variant to get
// the live register set under the 64-VGPR occupancy-doubling boundary BY
// CONSTRUCTION (float4 ring = 36 regs -> floor ~72 VGPR; float2 ring = 18).
//
// Wave = 64 lanes x 2 cols = 128 columns (120 outputs + 2 halo lanes/side).
// 9 strips x 120 = 1080 cols for W=1024 (5% waste vs round 4's 20%).
// Vertical: rolling 9-row window sum over a 16-row chunk, staged r[25]
// float2, all-static indices (rule #20). Halo re-reads L2/L3-absorbed.
// Horizontal: 9-tap from distance-1/2 lanes:
//   out.x = T(l-2) + T(l-1) + T(l) + T(l+1) + Vx(l+2)
//   out.y = Vy(l-2) + T(l-1) + T(l) + T(l+1) + T(l+2)
// 6 independent shuffles + 7 adds per 2 outputs. No LDS, no barriers.
//
// __launch_bounds__(256,8) pins VGPR<=64 -> 32 waves/CU; safe because the
// live set is genuinely < 64 (round 9's spill was live-set ~72 > cap).
// Tripwire: WRITE_SIZE > 120 MB = spill -> revert the cap.

constexpr int H = 1024, W = 1024;
constexpr int RAD = 4;
constexpr int OUTW = 120;               // (64 - 4 halo lanes) * 2 cols
constexpr int NSTRIP = 9;               // ceil(1024 / 120)
constexpr int CHUNK = 16;
constexpr int NCHUNK = H / CHUNK;       // 64
constexpr int NIMG = 24;                // 8 * 3
constexpr int NROWS = CHUNK + 2 * RAD + 1;  // 25

__global__ __launch_bounds__(256, 8) void box9_kernel(const float* __restrict__ x,
                                                      float* __restrict__ out) {
    const int lane = threadIdx.x & 63;
    const int wid  = blockIdx.x * 4 + (threadIdx.x >> 6);

    const int chunk = wid & (NCHUNK - 1);       // adjacent wids -> adjacent
    const int t     = wid >> 6;                 // chunks: halo rows L2-hot
    const int strip = t % NSTRIP;
    const int img   = t / NSTRIP;

    const int  cs  = strip * OUTW - 2 * RAD + lane * 2;  // first col (even -> 8B aligned)
    const bool cok = (cs >= 0) && (cs + 1 < W);
    const float* xp = x   + (size_t)img * (H * W) + (cok ? cs : 0);
    float*       op = out + (size_t)img * (H * W) + (cok ? cs : 0);

    const int h0 = chunk * CHUNK;

    // Stage chunk + vertical halo: 25 independent 8B loads; compiler sinks
    // to a ~9-row live window (18 VGPRs).
    float2 r[NROWS];
#pragma unroll
    for (int j = 0; j < NROWS; ++j) {
        const int row = h0 - RAD + j;
        r[j] = (cok && (unsigned)row < (unsigned)H)
             ? *reinterpret_cast<const float2*>(xp + (size_t)row * W)
             : make_float2(0.f, 0.f);
    }

    // V = vertical 9-row window sum, initialized over rows h0-4 .. h0+4.
    float2 V = make_float2(0.f, 0.f);
#pragma unroll
    for (int j = 0; j < 9; ++j) { V.x += r[j].x; V.y += r[j].y; }

    const bool sok = cok && (lane >= 2) && (lane <= 61);  // halo lanes don't store

#pragma unroll
    for (int j = 0; j < CHUNK; ++j) {
        const float T = V.x + V.y;
        // 6 INDEPENDENT shuffles (distance 1 and 2).
        const float Tm1 = __shfl(T,   lane - 1);
        const float Tp1 = __shfl(T,   lane + 1);
        const float Tm2 = __shfl(T,   lane - 2);
        const float Tp2 = __shfl(T,   lane + 2);
        const float Xp2 = __shfl(V.x, lane + 2);
        const float Ym2 = __shfl(V.y, lane - 2);

        const float M = Tm1 + T + Tp1;   // cols cs-2 .. cs+3
        float2 o;
        o.x = M + Tm2 + Xp2;             // col cs   : window cs-4 .. cs+4
        o.y = M + Ym2 + Tp2;             // col cs+1 : window cs-3 .. cs+5
        if (sok) *reinterpret_cast<float2*>(op + (size_t)(h0 + j) * W) = o;

        // Roll vertical window: add row h0+j+5, drop row h0+j-4 (static idx).
        V.x += r[j + 9].x - r[j].x;
        V.y += r[j + 9].y - r[j].y;
    }
}

extern "C" void kernel_launch(void* const* d_in, const int* in_sizes, int n_in,
                              void* d_out, int out_size, void* d_ws, size_t ws_size,
                              hipStream_t stream) {
    const float* x   = (const float*)d_in[0];
    float*       out = (float*)d_out;
    const int n_waves  = NIMG * NSTRIP * NCHUNK;   // 24*9*64 = 13824
    const int n_blocks = n_waves / 4;              // 3456 blocks -> 54 waves/CU
    box9_kernel<<<dim3(n_blocks), dim3(256), 0, stream>>>(x, out);
}

// Round 12
// 59.596 us; speedup vs baseline: 1.3947x; 1.3947x over previous
//
#include <hip/hip_runtime.h>

// 9x9 clipped box-SUM on (8,3,1024,1024) f32 — HORIZONTAL-FIRST, zero
// cross-lane ops.
//
// Plateau diagnosis (rounds 4-11): all vertical-first variants hit ~39.4us
// with VALUBusy ~10-17%, HBM ~65% of achievable, occupancy-insensitive,
// block-count-insensitive. Common factor: per-row V -> T -> 8 ds_bpermute
// (~100cy LDS-pipe latency) -> adds -> store serial chain. This kernel
// eliminates the cross-lane phase entirely.
//
// Each lane owns 4 cols (float4 at cs, cs%4==0). Horizontal 9-sum H for
// those 4 cols comes from 3 ALIGNED float4 loads (cols cs-4..cs+7, the
// +-16B spans are L1-hot — same cache lines as neighbors' center loads):
//   hx = sum9(a,b,c.x); hy = hx - a.x + c.y; ... (14 adds, lane-local)
// Vertical: V += H[j+9] - H[j]; V IS the output row (store directly).
// All H's depend only on loads -> serial chain per chunk = 16x8 adds;
// load latency overlaps across all 25 staged rows (round-4-proven sink
// pattern: full unroll, static indices, no breaks — rule #20).
//
// 4 strips x 256 cols = exactly W: zero lane waste, zero halo lanes.
// No LDS, no barriers, no shuffles, no launch_bounds cap (rounds 9/11:
// caps -> allocator spills; round 6: VGPR<=64 alone didn't help anyway).
// Tripwire: WRITE_SIZE > 120 MB = scratch spill -> revert.

constexpr int H = 1024, W = 1024;
constexpr int RAD = 4;
constexpr int CHUNK = 16;
constexpr int NCHUNK = H / CHUNK;           // 64
constexpr int NSTRIP = 4;                   // 4 x 256 cols = 1024 exact
constexpr int NIMG = 24;                    // 8 * 3
constexpr int NROWS = CHUNK + 2 * RAD + 1;  // 25
constexpr int HW = H * W;

__global__ __launch_bounds__(256) void box9_kernel(const float* __restrict__ x,
                                                   float* __restrict__ out) {
    const int lane = threadIdx.x & 63;
    const int wid  = blockIdx.x * 4 + (threadIdx.x >> 6);

    const int chunk = wid & (NCHUNK - 1);   // fastest-varying: adjacent wids
    const int rest  = wid >> 6;             // -> adjacent chunks, halo L2-hot
    const int strip = rest & (NSTRIP - 1);
    const int img   = rest >> 2;

    const int cs = strip * 256 + 4 * lane;  // own float4 col, always in-bounds
    const float* xp = x   + (size_t)img * HW + cs;
    float*       op = out + (size_t)img * HW + cs;

    const bool aok = (cs >= 4);             // left span exists (lane0/strip0: no)
    const bool bok = (cs + 7 < W);          // right span exists (lane63/strip3: no)

    const int h0 = chunk * CHUNK;

    // Per-row horizontal 9-sums for this lane's 4 cols; staged with static
    // indices, compiler sinks loads/compute to a ~10-row live window.
    float4 Hr[NROWS];
#pragma unroll
    for (int j = 0; j < NROWS; ++j) {
        const int row = h0 - RAD + j;
        float4 a = make_float4(0.f, 0.f, 0.f, 0.f);
        float4 b = a, c = a;
        if ((unsigned)row < (unsigned)H) {
            const float* rp = xp + (size_t)row * W;
            b = *reinterpret_cast<const float4*>(rp);
            if (aok) a = *reinterpret_cast<const float4*>(rp - 4);
            if (bok) c = *reinterpret_cast<const float4*>(rp + 4);
        }
        // Sliding 9-wide sums over the 12 floats [a|b|c].
        const float sb = b.x + b.y + b.z + b.w;
        float4 h;
        h.x = (a.x + a.y) + (a.z + a.w) + sb + c.x;  // cols cs-4..cs+4
        h.y = h.x - a.x + c.y;                       // cols cs-3..cs+5
        h.z = h.y - a.y + c.z;
        h.w = h.z - a.z + c.w;
        Hr[j] = h;
    }

    // V = vertical 9-row rolling sum of H == the output row itself.
    float4 V = make_float4(0.f, 0.f, 0.f, 0.f);
#pragma unroll
    for (int j = 0; j < 9; ++j) {
        V.x += Hr[j].x; V.y += Hr[j].y; V.z += Hr[j].z; V.w += Hr[j].w;
    }

#pragma unroll
    for (int j = 0; j < CHUNK; ++j) {
        *reinterpret_cast<float4*>(op + (size_t)(h0 + j) * W) = V;
        V.x += Hr[j + 9].x - Hr[j].x;
        V.y += Hr[j + 9].y - Hr[j].y;
        V.z += Hr[j + 9].z - Hr[j].z;
        V.w += Hr[j + 9].w - Hr[j].w;
    }
}

extern "C" void kernel_launch(void* const* d_in, const int* in_sizes, int n_in,
                              void* d_out, int out_size, void* d_ws, size_t ws_size,
                              hipStream_t stream) {
    const float* x   = (const float*)d_in[0];
    float*       out = (float*)d_out;
    const int n_waves  = NIMG * NSTRIP * NCHUNK;   // 24*4*64 = 6144
    const int n_blocks = n_waves / 4;              // 1536 blocks of 4 waves
    box9_kernel<<<dim3(n_blocks), dim3(256), 0, stream>>>(x, out);
}

// Round 13
// 45.496 us; speedup vs baseline: 1.8269x; 1.3099x over previous
//
#include <hip/hip_runtime.h>

// 9x9 clipped box-SUM on (8,3,1024,1024) f32 — horizontal-first with a
// 9-deep H ring (round-4's register discipline + round-12's shuffle-free
// math).
//
// Each lane owns the float4 at col cs (4 strips x 256 cols = exactly W;
// zero lane waste, zero halo lanes). Per row, the horizontal 9-sum H of the
// lane's 4 cols comes from 3 ALIGNED float4 loads (cols cs-4 .. cs+7); the
// +-16B spans are L1-hot (same cache lines as neighbor lanes' center
// loads). Vertical: V += H(h+5) - H(h-4) via a 9-entry ring Hr[j%9] —
// static indices under full unroll (rule #20), 36 VGPRs, identical
// register structure to round 4's proven r[9] live window.
//
// Critical path per output row: 2 adds + 1 store. No shuffles, no LDS,
// no barriers — the cross-lane phase that bounded rounds 4-11 is gone.
// All loads are address-independent -> freely hoistable by the scheduler.
//
// Lessons encoded: no launch_bounds cap (rounds 9/11: allocator spills);
// no >9-deep arrays (rounds 6/7/12: VGPR blowup).
// Tripwires: WRITE_SIZE >120MB = spill; VGPR >128 = residency halved.

constexpr int H = 1024, W = 1024;
constexpr int RAD = 4;
constexpr int CHUNK = 16;
constexpr int NCHUNK = H / CHUNK;           // 64
constexpr int NSTRIP = 4;                   // 4 x 256 cols = 1024 exact
constexpr int NIMG = 24;                    // 8 * 3
constexpr int HW = H * W;

__device__ __forceinline__ float4 computeH(const float* __restrict__ xp,
                                           int row, bool aok, bool bok) {
    float4 a = make_float4(0.f, 0.f, 0.f, 0.f);
    float4 b = a, c = a;
    if ((unsigned)row < (unsigned)H) {
        const float* rp = xp + (size_t)row * W;
        b = *reinterpret_cast<const float4*>(rp);
        if (aok) a = *reinterpret_cast<const float4*>(rp - 4);
        if (bok) c = *reinterpret_cast<const float4*>(rp + 4);
    }
    // Sliding 9-wide sums over the 12 floats [a|b|c].
    const float sb = b.x + b.y + b.z + b.w;
    float4 h;
    h.x = (a.x + a.y) + (a.z + a.w) + sb + c.x;  // cols cs-4 .. cs+4
    h.y = h.x - a.x + c.y;                       // cols cs-3 .. cs+5
    h.z = h.y - a.y + c.z;
    h.w = h.z - a.z + c.w;
    return h;
}

__global__ __launch_bounds__(256) void box9_kernel(const float* __restrict__ x,
                                                   float* __restrict__ out) {
    const int lane = threadIdx.x & 63;
    const int wid  = blockIdx.x * 4 + (threadIdx.x >> 6);

    const int chunk = wid & (NCHUNK - 1);   // fastest-varying: adjacent wids
    const int rest  = wid >> 6;             // -> adjacent chunks, halo L2-hot
    const int strip = rest & (NSTRIP - 1);
    const int img   = rest >> 2;

    const int cs = strip * 256 + 4 * lane;  // own float4 col, always in-bounds
    const float* xp = x   + (size_t)img * HW + cs;
    float*       op = out + (size_t)img * HW + cs;

    const bool aok = (cs >= 4);             // left span exists
    const bool bok = (cs + 7 < W);          // right span exists

    const int h0 = chunk * CHUNK;

    // Warm the 9-deep H ring with rows h0-4 .. h0+4; V = their sum.
    float4 Hr[9];
    float4 V = make_float4(0.f, 0.f, 0.f, 0.f);
#pragma unroll
    for (int j = 0; j < 9; ++j) {
        Hr[j] = computeH(xp, h0 - RAD + j, aok, bok);
        V.x += Hr[j].x; V.y += Hr[j].y; V.z += Hr[j].z; V.w += Hr[j].w;
    }

#pragma unroll
    for (int j = 0; j < CHUNK; ++j) {
        // V is the finished output row h0+j.
        *reinterpret_cast<float4*>(op + (size_t)(h0 + j) * W) = V;

        // Fresh H for the entering row (3 loads, issue-independent);
        // ring slot j%9 holds the leaving row's H (static index).
        const float4 Hn = computeH(xp, h0 + j + RAD + 1, aok, bok);
        V.x += Hn.x - Hr[j % 9].x;
        V.y += Hn.y - Hr[j % 9].y;
        V.z += Hn.z - Hr[j % 9].z;
        V.w += Hn.w - Hr[j % 9].w;
        Hr[j % 9] = Hn;
    }
}

extern "C" void kernel_launch(void* const* d_in, const int* in_sizes, int n_in,
                              void* d_out, int out_size, void* d_ws, size_t ws_size,
                              hipStream_t stream) {
    const float* x   = (const float*)d_in[0];
    float*       out = (float*)d_out;
    const int n_waves  = NIMG * NSTRIP * NCHUNK;   // 24*4*64 = 6144
    const int n_blocks = n_waves / 4;              // 1536 blocks of 4 waves
    box9_kernel<<<dim3(n_blocks), dim3(256), 0, stream>>>(x, out);
}

// Round 14
// 40.418 us; speedup vs baseline: 2.0565x; 1.1256x over previous
//
#include <hip/hip_runtime.h>

// 9x9 clipped box-SUM on (8,3,1024,1024) f32 — round-4 math (float4/lane,
// 8-shuffle horizontal) with CHUNK=32 and a PINNED register window:
// explicit 9-entry row ring (r[j%9], static idx) + explicit 4-deep prefetch
// queue (pf[j&3]). Goal: R8's reduced scheduled traffic (41 rows staged per
// 32 output rows = 219 MB total vs R4's 248 MB) at R4's register budget
// (R8's r[41] staging let the compiler hold ~20 rows live -> VGPR 120 ->
// occupancy fell -> rate fell 6.29 -> 5.6 TB/s, a wash).
//
// Model (fits rounds 4/8/13): duration = scheduled vector-mem bytes /
// 6.29 TB/s (the m13 copy ceiling) while VGPR <= ~100 keeps 16 waves/CU.
// Prediction: 219 MB -> ~35 us.
//
// Wave = 64 lanes x 4 cols = 256 columns (248 outputs + 4-col halo/side),
// 5 strips. Vertical: rolling 9-row window V via ring. Horizontal: 8
// independent shuffles, 2-deep adds. No LDS, no barriers, no launch_bounds
// caps (rounds 9/11: allocator spills under caps).
// Tripwires: WRITE_SIZE >120MB = spill; VGPR >128 = window not pinned.

constexpr int H = 1024, W = 1024;
constexpr int RAD = 4;
constexpr int OUTW = 248;               // (64 - 2 halo lanes) * 4 cols
constexpr int NSTRIP = 5;               // ceil(1024 / 248)
constexpr int CHUNK = 32;
constexpr int NCHUNK = H / CHUNK;       // 32
constexpr int NIMG = 24;                // 8 * 3

__global__ __launch_bounds__(256) void box9_kernel(const float* __restrict__ x,
                                                   float* __restrict__ out) {
    const int lane = threadIdx.x & 63;
    const int wid  = blockIdx.x * 4 + (threadIdx.x >> 6);

    const int chunk = wid & (NCHUNK - 1);       // adjacent wids -> adjacent
    const int t     = wid >> 5;                 // chunks: halo rows L2-hot
    const int strip = t % NSTRIP;
    const int img   = t / NSTRIP;

    const int  cs  = strip * OUTW - RAD + lane * 4;   // first col this lane holds
    const bool cok = (cs >= 0) && (cs + 3 < W);       // float4 always 16B-aligned
    const float* xp = x   + (size_t)img * (H * W) + (cok ? cs : 0);
    float*       op = out + (size_t)img * (H * W) + (cok ? cs : 0);

    const int h0 = chunk * CHUNK;

    auto ld = [&](int row) -> float4 {
        return (cok && (unsigned)row < (unsigned)H)
             ? *reinterpret_cast<const float4*>(xp + (size_t)row * W)
             : make_float4(0.f, 0.f, 0.f, 0.f);
    };

    // 9-entry ring: rows h0-4 .. h0+4. V = their sum.
    float4 r[9];
    float4 V = make_float4(0.f, 0.f, 0.f, 0.f);
#pragma unroll
    for (int j = 0; j < 9; ++j) {
        r[j] = ld(h0 - RAD + j);
        V.x += r[j].x; V.y += r[j].y; V.z += r[j].z; V.w += r[j].w;
    }

    // 4-deep prefetch queue: rows h0+5 .. h0+8 in flight.
    float4 pf[4];
#pragma unroll
    for (int k = 0; k < 4; ++k) pf[k] = ld(h0 + RAD + 1 + k);

    const bool sok = cok && (lane >= 1) && (lane <= 62);  // halo lanes don't store

#pragma unroll
    for (int j = 0; j < CHUNK; ++j) {
        // Row entering the window (loaded 4 iterations ago).
        const float4 n = pf[j & 3];
        // Refill the slot EARLY (consumed at j+4); rows beyond the last halo
        // row h0+CHUNK+4 are never loaded (compile-time guard per iteration).
        if (j + RAD + 5 <= CHUNK + RAD) pf[j & 3] = ld(h0 + j + RAD + 5);

        // Own prefix/suffix sums of V (3-deep).
        const float p0 = V.x, p1 = p0 + V.y, p2 = p1 + V.z, T = p2 + V.w;
        const float s3 = V.w, s2 = s3 + V.z, s1 = s2 + V.y;
        // 8 INDEPENDENT shuffles: suffixes from left lane, prefixes from right.
        const float L0 = __shfl(T,  lane - 1);
        const float L1 = __shfl(s1, lane - 1);
        const float L2 = __shfl(s2, lane - 1);
        const float L3 = __shfl(s3, lane - 1);
        const float R0 = __shfl(p0, lane + 1);
        const float R1 = __shfl(p1, lane + 1);
        const float R2 = __shfl(p2, lane + 1);
        const float R3 = __shfl(T,  lane + 1);
        float4 o;
        o.x = L0 + T + R0;   // 9-wide horizontal windows for cols cs..cs+3
        o.y = L1 + T + R1;
        o.z = L2 + T + R2;
        o.w = L3 + T + R3;
        if (sok) *reinterpret_cast<float4*>(op + (size_t)(h0 + j) * W) = o;

        // Roll vertical window: slot j%9 holds the leaving row h0+j-4.
        V.x += n.x - r[j % 9].x;
        V.y += n.y - r[j % 9].y;
        V.z += n.z - r[j % 9].z;
        V.w += n.w - r[j % 9].w;
        r[j % 9] = n;
    }
}

extern "C" void kernel_launch(void* const* d_in, const int* in_sizes, int n_in,
                              void* d_out, int out_size, void* d_ws, size_t ws_size,
                              hipStream_t stream) {
    const float* x   = (const float*)d_in[0];
    float*       out = (float*)d_out;
    const int n_waves  = NIMG * NSTRIP * NCHUNK;   // 24*5*32 = 3840
    const int n_blocks = n_waves / 4;              // 960 blocks of 4 waves
    box9_kernel<<<dim3(n_blocks), dim3(256), 0, stream>>>(x, out);
}

// Round 15
// 39.158 us; speedup vs baseline: 2.1226x; 1.0322x over previous
//
#include <hip/hip_runtime.h>

// 9x9 clipped box-SUM on (8,3,1024,1024) f32 — FINAL: round-4 structure,
// the measured optimum across 14 structural variants (39.4us).
//
// Roofline argument (fits all rounds):
//   duration = scheduled vector-mem bytes / rate, where rate <= 6.29 TB/s
//   (m13 copy ceiling) and rate degrades when grid-supplied waves/CU < ~30.
//   CHUNK=16 is the unique point supplying 30 waves/CU (7680 waves); its
//   scheduled bytes = 96MB * 25/16 (vertical halo) + 98MB writes = 248MB
//   -> 39.4us at the ceiling. Round 4 measured 39.38us = within 1%.
//   CHUNK=32 (219MB) supplies only 15 waves/CU -> rate 5.4-5.6 TB/s (wash).
//   Register caps spill (R9/R11); extra register state kills occupancy
//   (R6/R7/R12); shuffle-free trades 3x load issue (R13); LDS cooperation
//   costs barriers (R5/R6).
//
// Wave = 64 lanes x 4 cols = 256 columns (248 outputs + 4-col halo/side).
// Vertical: rolling 9-row window sum over a 16-row chunk, staged r[25],
// fully-static indices (rule #20) — compiler sinks loads to a ~9-row live
// window (VGPR 72). Horizontal: out[k] = sfx_left[k] + T + pfx_right[k]
// via 8 independent shuffles, 2-deep add chain. No LDS, no barriers.

constexpr int H = 1024, W = 1024;
constexpr int RAD = 4;
constexpr int OUTW = 248;               // (64 - 2 halo lanes) * 4 cols
constexpr int NSTRIP = 5;               // ceil(1024 / 248)
constexpr int CHUNK = 16;
constexpr int NCHUNK = H / CHUNK;       // 64
constexpr int NIMG = 24;                // 8 * 3
constexpr int NROWS = CHUNK + 2 * RAD + 1;  // 25

__global__ __launch_bounds__(256) void box9_kernel(const float* __restrict__ x,
                                                   float* __restrict__ out) {
    const int lane = threadIdx.x & 63;
    const int wid  = blockIdx.x * 4 + (threadIdx.x >> 6);

    const int chunk = wid & (NCHUNK - 1);       // adjacent wids -> adjacent
    const int t     = wid >> 6;                 // chunks: halo rows L2-hot
    const int strip = t % NSTRIP;
    const int img   = t / NSTRIP;

    const int  cs  = strip * OUTW - RAD + lane * 4;   // first col this lane holds
    const bool cok = (cs >= 0) && (cs + 3 < W);       // float4 always 16B-aligned
    const float* xp = x   + (size_t)img * (H * W) + (cok ? cs : 0);
    float*       op = out + (size_t)img * (H * W) + (cok ? cs : 0);

    const int h0 = chunk * CHUNK;

    // Stage the whole chunk (+ vertical halo) in registers: 25 independent
    // loads; compiler sinks them into the loop keeping ~9 rows live.
    float4 r[NROWS];
#pragma unroll
    for (int j = 0; j < NROWS; ++j) {
        const int row = h0 - RAD + j;
        r[j] = (cok && (unsigned)row < (unsigned)H)
             ? *reinterpret_cast<const float4*>(xp + (size_t)row * W)
             : make_float4(0.f, 0.f, 0.f, 0.f);
    }

    // V = vertical 9-row window sum, initialized over rows h0-4 .. h0+4.
    float4 V = make_float4(0.f, 0.f, 0.f, 0.f);
#pragma unroll
    for (int j = 0; j < 9; ++j) {
        V.x += r[j].x; V.y += r[j].y; V.z += r[j].z; V.w += r[j].w;
    }

    const bool sok = cok && (lane >= 1) && (lane <= 62);  // halo lanes don't store

#pragma unroll
    for (int j = 0; j < CHUNK; ++j) {
        // Own prefix/suffix sums of V (3-deep).
        const float p0 = V.x, p1 = p0 + V.y, p2 = p1 + V.z, T = p2 + V.w;
        const float s3 = V.w, s2 = s3 + V.z, s1 = s2 + V.y;
        // 8 INDEPENDENT shuffles: suffixes from left lane, prefixes from right.
        const float L0 = __shfl(T,  lane - 1);
        const float L1 = __shfl(s1, lane - 1);
        const float L2 = __shfl(s2, lane - 1);
        const float L3 = __shfl(s3, lane - 1);
        const float R0 = __shfl(p0, lane + 1);
        const float R1 = __shfl(p1, lane + 1);
        const float R2 = __shfl(p2, lane + 1);
        const float R3 = __shfl(T,  lane + 1);
        float4 o;
        o.x = L0 + T + R0;   // 9-wide horizontal windows for cols cs..cs+3
        o.y = L1 + T + R1;
        o.z = L2 + T + R2;
        o.w = L3 + T + R3;
        if (sok) *reinterpret_cast<float4*>(op + (size_t)(h0 + j) * W) = o;

        // Roll vertical window: add row h0+j+5, drop row h0+j-4 (static idx).
        V.x += r[j + 9].x - r[j].x;
        V.y += r[j + 9].y - r[j].y;
        V.z += r[j + 9].z - r[j].z;
        V.w += r[j + 9].w - r[j].w;
    }
}

extern "C" void kernel_launch(void* const* d_in, const int* in_sizes, int n_in,
                              void* d_out, int out_size, void* d_ws, size_t ws_size,
                              hipStream_t stream) {
    const float* x   = (const float*)d_in[0];
    float*       out = (float*)d_out;
    const int n_waves  = NIMG * NSTRIP * NCHUNK;   // 24*5*64 = 7680
    const int n_blocks = n_waves / 4;              // 1920 blocks -> 30 waves/CU
    box9_kernel<<<dim3(n_blocks), dim3(256), 0, stream>>>(x, out);
}